// Round 10
// baseline (421.687 us; speedup 1.0000x reference)
//
#include <hip/hip_runtime.h>

// ---------------------------------------------------------------------------
// 2-layer GCN (DGL GraphConv, norm='both') on MI355X.
// Round 10: XCD-sliced SpMM. r9's spmm was fabric-BW-bound: random src =>
// every XCD gathers nearly all of Y (FETCH 183MB = 7x the 25.6MB buffer,
// 2.8TB/s beyond-L2). Fix: Y stored as 8 column-planes [plane][node][16]
// (3.2MB/plane fits one XCD's 4MB L2); spmm grid bid&7 -> plane, so each
// XCD gathers only its own plane => L2-hit gathers. Indices bpermute-
// redistributed, 8-deep unrolled u16 gather. GEMM epilogue writes the
// plane layout (same store count). Everything else unchanged from r9.
// ---------------------------------------------------------------------------

#define RS_LOG 10
#define RS (1 << RS_LOG)  // 1024 nodes per range
#define EPB 4096

typedef short bf16x8 __attribute__((ext_vector_type(8)));
typedef float f32x4 __attribute__((ext_vector_type(4)));

__device__ __forceinline__ unsigned short rne_bf16(float v) {
  unsigned u = __float_as_uint(v);
  return (unsigned short)((u + 0x7FFF + ((u >> 16) & 1)) >> 16);
}

__device__ __forceinline__ void load_lds16(const void* g, void* l) {
  __builtin_amdgcn_global_load_lds((const __attribute__((address_space(1))) unsigned*)g,
                                   (__attribute__((address_space(3))) unsigned*)l, 16, 0, 0);
}

// ---------------- legacy fallback build (round-3 proven) ----------------
__global__ void build_graph(const int* __restrict__ src, const int* __restrict__ dst,
                            int* __restrict__ cursor, int* __restrict__ deg_out,
                            int* __restrict__ padded, int E, int CAP) {
  int e = blockIdx.x * blockDim.x + threadIdx.x;
  if (e < E) {
    int s = src[e];
    int d = dst[e];
    atomicAdd(&deg_out[s], 1);
    int pos = atomicAdd(&cursor[d], 1);
    if (pos < CAP) padded[(size_t)d * CAP + pos] = s;
  }
}

// ---------------- phase A: partition with LDS counting-sort --------------
__global__ __launch_bounds__(256) void partition_edges(
    const int* __restrict__ src, const int* __restrict__ dst, int* __restrict__ g_cnt,
    int* __restrict__ part_dst, unsigned short* __restrict__ part_src, int E, int NR, int CAPR) {
  __shared__ int cntD[256], locD[256], baseD[256];
  __shared__ int cntS[256], locS[256], baseS[256];
  __shared__ unsigned stageD[EPB];
  __shared__ unsigned short stageS[EPB];
  __shared__ unsigned char rngD[EPB], rngS[EPB];
  int t = threadIdx.x;
  int e0 = blockIdx.x * EPB;
  int e1 = min(e0 + EPB, E);
  int nE = e1 - e0;
  cntD[t] = 0;
  cntS[t] = 0;
  __syncthreads();
  for (int e = e0 + t; e < e1; e += 256) {
    atomicAdd(&cntD[dst[e] >> RS_LOG], 1);
    atomicAdd(&cntS[src[e] >> RS_LOG], 1);
  }
  __syncthreads();
  locD[t] = cntD[t];
  locS[t] = cntS[t];
  __syncthreads();
  for (int ofs = 1; ofs < 256; ofs <<= 1) {
    int aD = (t >= ofs) ? locD[t - ofs] : 0;
    int aS = (t >= ofs) ? locS[t - ofs] : 0;
    __syncthreads();
    locD[t] += aD;
    locS[t] += aS;
    __syncthreads();
  }
  int exD = locD[t] - cntD[t];
  int exS = locS[t] - cntS[t];
  __syncthreads();
  locD[t] = exD;
  locS[t] = exS;
  if (t < NR) {
    baseD[t] = atomicAdd(&g_cnt[t * 16], cntD[t]);
    baseS[t] = atomicAdd(&g_cnt[(NR + t) * 16], cntS[t]);
  }
  cntD[t] = 0;
  cntS[t] = 0;
  __syncthreads();
  for (int e = e0 + t; e < e1; e += 256) {
    int s = src[e];
    int d = dst[e];
    int rd = d >> RS_LOG;
    int rs = s >> RS_LOG;
    int pd = locD[rd] + atomicAdd(&cntD[rd], 1);
    stageD[pd] = ((unsigned)(d & (RS - 1)) << 17) | (unsigned)s;
    rngD[pd] = (unsigned char)rd;
    int ps = locS[rs] + atomicAdd(&cntS[rs], 1);
    stageS[ps] = (unsigned short)(s & (RS - 1));
    rngS[ps] = (unsigned char)rs;
  }
  __syncthreads();
  for (int i = t; i < nE; i += 256) {
    int r = rngD[i];
    int pos = baseD[r] + (i - locD[r]);
    if (pos < CAPR) part_dst[(size_t)r * CAPR + pos] = stageD[i];
    int r2 = rngS[i];
    int pos2 = baseS[r2] + (i - locS[r2]);
    if (pos2 < CAPR) part_src[(size_t)r2 * CAPR + pos2] = stageS[i];
  }
}

// ---------------- phase B: per-range CSR build + src histogram ----------
__global__ __launch_bounds__(512) void build_structures(
    const int* __restrict__ g_cnt, const int* __restrict__ part_dst,
    const unsigned short* __restrict__ part_src, int* __restrict__ padded,
    int* __restrict__ deg_in, int* __restrict__ deg_out, int N, int NR, int CAPR, int CAP) {
  __shared__ int cur[RS];
  int t = threadIdx.x;
  int b = blockIdx.x;
  for (int i = t; i < RS; i += 512) cur[i] = 0;
  __syncthreads();
  if (b < NR) {
    int cnt = min(g_cnt[b * 16], CAPR);
    const int* p = part_dst + (size_t)b * CAPR;
    for (int i = t; i < cnt; i += 512) {
      int v = p[i];
      int dlow = v >> 17;
      int s = v & 0x1FFFF;
      int pos = atomicAdd(&cur[dlow], 1);
      if (pos < CAP) padded[((size_t)((b << RS_LOG) + dlow)) * CAP + pos] = s;
    }
    __syncthreads();
    int nbase = b << RS_LOG;
    for (int i = t; i < RS; i += 512) {
      int node = nbase + i;
      if (node < N) deg_in[node] = cur[i];
    }
  } else {
    int r = b - NR;
    int cnt = min(g_cnt[(NR + r) * 16], CAPR);
    const unsigned short* p = part_src + (size_t)r * CAPR;
    for (int i = t; i < cnt; i += 512) atomicAdd(&cur[p[i]], 1);
    __syncthreads();
    int nbase = r << RS_LOG;
    for (int i = t; i < RS; i += 512) {
      int node = nbase + i;
      if (node < N) deg_out[node] = cur[i];
    }
  }
}

__global__ void compute_norms(const int* __restrict__ deg_out, const int* __restrict__ deg_in,
                              float* __restrict__ norm_src, float* __restrict__ norm_dst, int N) {
  int i = blockIdx.x * blockDim.x + threadIdx.x;
  if (i < N) {
    norm_src[i] = rsqrtf((float)max(deg_out[i], 1));
    norm_dst[i] = rsqrtf((float)max(deg_in[i], 1));
  }
}

// ---- one-time W prep: hi/lo bf16 split, packed in LANE-MAJOR frag order.
__global__ __launch_bounds__(256) void prep_w_frag(const float* __restrict__ W,
                                                   unsigned short* __restrict__ Wfrag) {
  int idx = blockIdx.x * 256 + threadIdx.x;  // 16384 = 32 chunks x 64 lanes x 8 j
  int j = idx & 7;
  int l = (idx >> 3) & 63;
  int chunk = idx >> 9;
  int nr = chunk >> 2;
  int s = chunk & 3;
  int col = nr * 16 + (l & 15);
  int k = s * 32 + (l >> 4) * 8 + j;
  float w = W[k * 128 + col];
  unsigned short h = rne_bf16(w);
  float hf = __uint_as_float((unsigned)h << 16);
  unsigned short lo = rne_bf16(w - hf);
  Wfrag[((chunk * 2 + 0) * 64 + l) * 8 + j] = h;
  Wfrag[((chunk * 2 + 1) * 64 + l) * 8 + j] = lo;
}

// ---- persistent-block GEMM: Yp[plane][node][16] = bf16(norm*(X@W)).
// Same as round 9 except the epilogue writes the 8-plane column-sliced
// layout consumed by spmm_sliced (plane = global col-tile index).
__global__ __launch_bounds__(512, 1) void gemm_mfma_p(const float* __restrict__ X,
                                                      const unsigned short* __restrict__ Wfrag,
                                                      const float* __restrict__ norm,
                                                      unsigned short* __restrict__ Yp, int N) {
  extern __shared__ unsigned char smem[];
  unsigned char* Wl = smem;          // 64KB
  unsigned char* Xa = smem + 65536;  // 32KB
  unsigned char* Xb = smem + 98304;  // 32KB
  int t = threadIdx.x;
  int lane = t & 63;
  int wv = t >> 6;

#pragma unroll
  for (int j = 0; j < 8; j++) {
    int d = j * 8192 + t * 16;
    load_lds16((const unsigned char*)Wfrag + d, Wl + d);
  }

  auto stage = [&](unsigned char* dstb, int tr0) {
    long vb = ((long)N - tr0) * 512;
    const unsigned char* xbase = (const unsigned char*)X + (size_t)tr0 * 512;
#pragma unroll
    for (int j = 0; j < 4; j++) {
      int d = j * 8192 + t * 16;
      int off = d ^ (((d >> 9) & 7) << 4);
      long o = off;
      if (o >= vb) o = 0;
      load_lds16(xbase + o, dstb + d);
    }
  };

  int tile = blockIdx.x;
  stage(Xa, tile * 64);
  asm volatile("s_waitcnt vmcnt(0)" ::: "memory");
  __syncthreads();

  int c = lane & 15;
  int kgrp = lane >> 4;
  int g = wv & 3;
  int nb = (wv >> 2) * 4;
  unsigned char* Xcur = Xa;
  unsigned char* Xnxt = Xb;

  for (; tile * 64 < N; tile += gridDim.x) {
    int tr0 = tile * 64;
    int nxt_r0 = (tile + gridDim.x) * 64;
    if (nxt_r0 < N) stage(Xnxt, nxt_r0);

    int rloc = g * 16 + c;
    int rowA = tr0 + rloc;
    float nn = (rowA < N) ? norm[rowA] : 0.f;
    f32x4 acc[4];
#pragma unroll
    for (int nr = 0; nr < 4; nr++) acc[nr] = (f32x4){0.f, 0.f, 0.f, 0.f};

#pragma unroll
    for (int s = 0; s < 4; s++) {
      int byteA = rloc * 512 + (s * 32 + kgrp * 8) * 4;
      int a0 = byteA ^ ((rloc & 7) << 4);
      float4 xa = *(const float4*)(Xcur + a0);
      float4 xb2 = *(const float4*)(Xcur + (a0 ^ 16));
      bf16x8 ah, al;
      {
        float v[8] = {xa.x, xa.y, xa.z, xa.w, xb2.x, xb2.y, xb2.z, xb2.w};
#pragma unroll
        for (int j = 0; j < 8; j++) {
          float a = v[j] * nn;
          unsigned short h = rne_bf16(a);
          ah[j] = (short)h;
          al[j] = (short)rne_bf16(a - __uint_as_float((unsigned)h << 16));
        }
      }
#pragma unroll
      for (int nr = 0; nr < 4; nr++) {
        int chunk = (nb + nr) * 4 + s;
        bf16x8 bh = *(const bf16x8*)(Wl + (chunk * 2 + 0) * 1024 + lane * 16);
        bf16x8 bl = *(const bf16x8*)(Wl + (chunk * 2 + 1) * 1024 + lane * 16);
        acc[nr] = __builtin_amdgcn_mfma_f32_16x16x32_bf16(ah, bh, acc[nr], 0, 0, 0);
        acc[nr] = __builtin_amdgcn_mfma_f32_16x16x32_bf16(al, bh, acc[nr], 0, 0, 0);
        acc[nr] = __builtin_amdgcn_mfma_f32_16x16x32_bf16(ah, bl, acc[nr], 0, 0, 0);
      }
    }

    asm volatile("s_waitcnt vmcnt(0)" ::: "memory");
    __syncthreads();

    // plane-major store: Yp[plane][row][c], plane = nb+nr
    int rb = tr0 + g * 16 + kgrp * 4;
#pragma unroll
    for (int q = 0; q < 4; q++) {
      int row = rb + q;
      if (row < N) {
#pragma unroll
        for (int nr = 0; nr < 4; nr++) {
          Yp[(size_t)(nb + nr) * N * 16 + (size_t)row * 16 + c] = rne_bf16(acc[nr][q]);
        }
      }
    }
    unsigned char* tmp = Xcur;
    Xcur = Xnxt;
    Xnxt = tmp;
  }
}

// ---- XCD-sliced SpMM: out[v, slice*16+il] from plane Yp[slice].
// Grid: bid&7 = slice (round-robin XCD => per-XCD L2-resident 3.2MB plane),
// bid>>3 = 16-node chunk. Wave = 4 nodes x 16 cols; indices loaded 16/round,
// redistributed by ds_bpermute; 8-deep unrolled u16 gathers.
__global__ __launch_bounds__(256) void spmm_sliced(const unsigned short* __restrict__ Yp,
                                                   const int* __restrict__ padded,
                                                   const int* __restrict__ deg_in,
                                                   const float* __restrict__ norm_dst,
                                                   const float* __restrict__ bias,
                                                   float* __restrict__ out, int N, int CAP,
                                                   int do_relu) {
  int t = threadIdx.x;
  int lane = t & 63;
  int wv = t >> 6;
  int slice = blockIdx.x & 7;
  int chunk = blockIdx.x >> 3;
  int g = lane >> 4;   // node sub-group 0..3
  int il = lane & 15;  // col within slice
  int v = chunk * 16 + wv * 4 + g;
  bool okv = v < N;
  int cnt = okv ? min(deg_in[v], CAP) : 0;
  int mc = max(cnt, __shfl_xor(cnt, 16));
  mc = max(mc, __shfl_xor(mc, 32));

  const unsigned short* plane = Yp + (size_t)slice * N * 16;
  float acc = 0.f;
  for (int r = 0; r * 16 < mc; r++) {
    int slot = r * 16 + il;
    int sidx = (okv && slot < cnt) ? padded[(size_t)v * CAP + slot] : 0;
    int lim = min(mc - r * 16, 16);
    for (int i0 = 0; i0 < lim; i0 += 8) {
      int s_[8];
      int act_[8];
#pragma unroll
      for (int u = 0; u < 8; u++) {
        int i = i0 + u;
        int s = __builtin_amdgcn_ds_bpermute((g * 16 + (i & 15)) * 4, sidx);
        int a = (r * 16 + i) < cnt;
        s_[u] = a ? s : 0;
        act_[u] = a;
      }
      float w_[8];
#pragma unroll
      for (int u = 0; u < 8; u++) {
        unsigned w = (unsigned)plane[(size_t)s_[u] * 16 + il];
        w_[u] = __uint_as_float(w << 16);
      }
#pragma unroll
      for (int u = 0; u < 8; u++) acc += act_[u] ? w_[u] : 0.f;
    }
  }
  if (okv) {
    float nd = norm_dst[v];
    float bb = bias[slice * 16 + il];
    float rres = acc * nd + bb;
    if (do_relu) rres = fmaxf(rres, 0.f);
    out[(size_t)v * 128 + slice * 16 + il] = rres;
  }
}

extern "C" void kernel_launch(void* const* d_in, const int* in_sizes, int n_in,
                              void* d_out, int out_size, void* d_ws, size_t ws_size,
                              hipStream_t stream) {
  const float* feature = (const float*)d_in[0];
  const int* src = (const int*)d_in[1];
  const int* dst = (const int*)d_in[2];
  const float* W1 = (const float*)d_in[3];
  const float* b1 = (const float*)d_in[4];
  const float* W2 = (const float*)d_in[5];
  const float* b2 = (const float*)d_in[6];
  float* out = (float*)d_out;

  const int F = 128;
  int N = in_sizes[0] / F;
  int E = in_sizes[1];
  (void)n_in;
  (void)out_size;

  char* ws = (char*)d_ws;
  size_t off = 0;
  auto alloc = [&](size_t bytes) -> char* {
    char* p = ws + off;
    off = (off + bytes + 255) & ~(size_t)255;
    return p;
  };
  float* h_buf = (float*)alloc((size_t)N * F * 4);  // 51.2 MB
  int* degs = (int*)alloc((size_t)2 * N * 4);       // contiguous: deg_in|deg_out
  int* deg_in_ = degs;                              // legacy path: doubles as cursor
  int* deg_out_ = degs + N;
  float* norm_src = (float*)alloc((size_t)N * 4);
  float* norm_dst = (float*)alloc((size_t)N * 4);
  unsigned short* wfrag1 = (unsigned short*)alloc(32768 * 2);  // 64KB
  unsigned short* wfrag2 = (unsigned short*)alloc(32768 * 2);

  int NR = (N + RS - 1) >> RS_LOG;
  int CAPR = (E + NR - 1) / NR + 4096;
  CAPR = (CAPR + 31) & ~31;
  size_t part_bytes =
      (size_t)NR * CAPR * 4 + (size_t)NR * CAPR * 2 + (size_t)2 * NR * 16 * 4 + 1024;
  size_t avail = (ws_size > off) ? ws_size - off : 0;

  int CAP;
  bool partition_ok = (N <= 131072) && (NR <= 255);
  bool use_part;
  if (partition_ok && avail >= (size_t)N * 64 * 4 + part_bytes) {
    CAP = 64;
    use_part = true;
  } else if (partition_ok && avail >= (size_t)N * 48 * 4 + part_bytes) {
    CAP = 48;
    use_part = true;
  } else if (avail >= (size_t)N * 64 * 4 + (size_t)N * 4 + 256) {
    CAP = 64;
    use_part = false;
  } else if (avail >= (size_t)N * 48 * 4 + (size_t)N * 4 + 256) {
    CAP = 48;
    use_part = false;
  } else {
    CAP = 32;
    use_part = false;
  }
  int* padded = (int*)alloc((size_t)N * CAP * 4);

  prep_w_frag<<<64, 256, 0, stream>>>(W1, wfrag1);
  prep_w_frag<<<64, 256, 0, stream>>>(W2, wfrag2);

  if (use_part) {
    int* part_dst = (int*)alloc((size_t)NR * CAPR * 4);
    unsigned short* part_src = (unsigned short*)alloc((size_t)NR * CAPR * 2);
    int* g_cnt = (int*)alloc((size_t)2 * NR * 16 * 4);
    int NB = (E + EPB - 1) / EPB;
    hipMemsetAsync(g_cnt, 0, (size_t)2 * NR * 16 * 4, stream);
    partition_edges<<<NB, 256, 0, stream>>>(src, dst, g_cnt, part_dst, part_src, E, NR, CAPR);
    build_structures<<<2 * NR, 512, 0, stream>>>(g_cnt, part_dst, part_src, padded, deg_in_,
                                                 deg_out_, N, NR, CAPR, CAP);
  } else {
    int* cursor = (int*)alloc((size_t)N * 4);
    hipMemsetAsync(degs, 0, (size_t)2 * N * 4, stream);
    build_graph<<<(E + 255) / 256, 256, 0, stream>>>(src, dst, deg_in_, deg_out_, padded, E, CAP);
    (void)cursor;
  }
  compute_norms<<<(N + 255) / 256, 256, 0, stream>>>(deg_out_, deg_in_, norm_src, norm_dst, N);

  // Y plane buffers: y1 in d_out (dead until final store); y2 from ws if it
  // fits, else d_out + final d2d copy.
  unsigned short* ybf1 = (unsigned short*)d_out;
  unsigned short* ybf2;
  float* final_target;
  bool need_copy;
  size_t ybf_bytes = (size_t)N * 128 * 2;
  if (ws_size > off && ws_size - off >= ybf_bytes + 256) {
    ybf2 = (unsigned short*)alloc(ybf_bytes);
    final_target = out;
    need_copy = false;
  } else {
    ybf2 = (unsigned short*)d_out;
    final_target = h_buf;
    need_copy = true;
  }

  int ntiles = (N + 63) / 64;
  int gb = ntiles < 256 ? ntiles : 256;
  int schunks = (N + 15) / 16;
  // layer 1
  gemm_mfma_p<<<gb, 512, 131072, stream>>>(feature, wfrag1, norm_src, ybf1, N);
  spmm_sliced<<<schunks * 8, 256, 0, stream>>>(ybf1, padded, deg_in_, norm_dst, b1, h_buf, N,
                                               CAP, 1);
  // layer 2
  gemm_mfma_p<<<gb, 512, 131072, stream>>>(h_buf, wfrag2, norm_src, ybf2, N);
  spmm_sliced<<<schunks * 8, 256, 0, stream>>>(ybf2, padded, deg_in_, norm_dst, b2, final_target,
                                               N, CAP, 0);
  if (need_copy) {
    hipMemcpyAsync(out, h_buf, (size_t)N * F * 4, hipMemcpyDeviceToDevice, stream);
  }
}